// Round 10
// baseline (591.160 us; speedup 1.0000x reference)
//
#include <hip/hip_runtime.h>
#include <hip/hip_bf16.h>
#include <math.h>

#define BATCH 2
#define SEQL 2048
#define T 4096            // BATCH*SEQL tokens
#define DMODEL 1024
#define DINNER 2048
#define DSTATE 128
#define NH 32
#define HD 64
#define DPROJ2 4352       // z (2048) + xBC (2304); dt handled separately in fp32
#define CONVCH 2304
#define NCH 16            // chunks per sequence
#define CHUNK 128
#define EPS 1e-5f

#define N_INW ((size_t)DPROJ2 * DMODEL)   // 4,456,448
#define N_OUTW ((size_t)DMODEL * DINNER)  // 2,097,152
#define N_ST ((size_t)BATCH * NCH * NH * HD * DSTATE)  // 8,388,608 per dir
#define F2B_BLOCKS 10752   // (2*N_INW + N_OUTW)/4/256
#define TW_BLOCKS 1024     // 32 x 16 x 2

typedef unsigned short u16;
typedef __bf16 bf16x8 __attribute__((ext_vector_type(8)));
typedef float f32x4 __attribute__((ext_vector_type(4)));

__device__ __forceinline__ u16 f2b(float f) {
    union { float f; unsigned u; } v; v.f = f;
    unsigned r = v.u + 0x7fffu + ((v.u >> 16) & 1u);
    return (u16)(r >> 16);
}
__device__ __forceinline__ float b2f(u16 b) {
    union { unsigned u; float f; } v; v.u = ((unsigned)b) << 16;
    return v.f;
}
__device__ __forceinline__ int flipseq(int r) {
    return (r & ~(SEQL - 1)) | ((SEQL - 1) - (r & (SEQL - 1)));
}
__device__ __forceinline__ void gload16(const u16* g, u16* l) {
    __builtin_amdgcn_global_load_lds(
        (const __attribute__((address_space(1))) void*)g,
        (__attribute__((address_space(3))) void*)l, 16, 0, 0);
}

// ---------------- block reduce ----------------
__device__ __forceinline__ float blockReduceSum(float v) {
    __shared__ float red_[4];
    for (int off = 32; off > 0; off >>= 1) v += __shfl_down(v, off);
    int lane = threadIdx.x & 63, wid = threadIdx.x >> 6;
    if (lane == 0) red_[wid] = v;
    __syncthreads();
    if (threadIdx.x == 0) {
        float s = 0.f;
        int nw = blockDim.x >> 6;
        for (int i = 0; i < nw; ++i) s += red_[i];
        red_[0] = s;
    }
    __syncthreads();
    return red_[0];
}

// ---------------- input rmsnorm -> bf16 ----------------
__global__ __launch_bounds__(256) void k_rmsnorm(
    const float* __restrict__ x, const float* __restrict__ w,
    u16* __restrict__ outb)
{
    int row = blockIdx.x;
    const float* xr = x + (size_t)row * DMODEL;
    float ss = 0.f;
    for (int i = threadIdx.x; i < DMODEL; i += 256) { float v = xr[i]; ss += v * v; }
    float tot = blockReduceSum(ss);
    float sc = rsqrtf(tot / DMODEL + EPS);
    for (int i = threadIdx.x; i < DMODEL; i += 256)
        outb[(size_t)row * DMODEL + i] = f2b(xr[i] * sc * w[i]);
}

// ---------------- weight prep: f2b (in_w x2, out_w_blk) + transpose out_w, one dispatch ----------------
__global__ __launch_bounds__(256) void k_wprep(
    const float* __restrict__ f_in_w, const float* __restrict__ b_in_w,
    const float* __restrict__ out_w_blk,
    const float* __restrict__ f_out_w, const float* __restrict__ b_out_w,
    u16* __restrict__ d_inwb, u16* __restrict__ d_owbb, u16* __restrict__ d_fowT)
{
    __shared__ u16 t[64][65];
    int bid = blockIdx.x;
    if (bid < F2B_BLOCKS) {
        size_t i = ((size_t)bid * 256 + threadIdx.x) * 4;
        const float* s; u16* d; size_t off;
        if (i < 2 * N_INW) {
            int dir = i >= N_INW;
            off = i - (size_t)dir * N_INW;
            s = dir ? b_in_w : f_in_w; d = d_inwb + (size_t)dir * N_INW;
        } else {
            off = i - 2 * N_INW;
            if (off >= N_OUTW) return;
            s = out_w_blk; d = d_owbb;
        }
        float4 v = *(const float4*)(s + off);
        ushort4 o;
        o.x = f2b(v.x); o.y = f2b(v.y); o.z = f2b(v.z); o.w = f2b(v.w);
        *(ushort4*)(d + off) = o;
        return;
    }
    // transpose part: out_w (1024 x 2048) -> (2048 x 1024) bf16
    int b2 = bid - F2B_BLOCKS;
    int dir = b2 >> 9;
    int rem = b2 & 511;
    int c0 = (rem & 31) * 64, e0 = (rem >> 5) * 64;
    const float* src = dir ? b_out_w : f_out_w;
    u16* d = d_fowT + (size_t)dir * N_OUTW;
    for (int i = threadIdx.x; i < 64 * 16; i += 256) {
        int el = i >> 4, c4 = (i & 15) * 4;
        float4 v = *(const float4*)(src + (size_t)(e0 + el) * DINNER + c0 + c4);
        t[c4 + 0][el] = f2b(v.x); t[c4 + 1][el] = f2b(v.y);
        t[c4 + 2][el] = f2b(v.z); t[c4 + 3][el] = f2b(v.w);
    }
    __syncthreads();
    for (int i = threadIdx.x; i < 64 * 16; i += 256) {
        int cl = i >> 4, e4 = (i & 15) * 4;
        ushort4 o;
        o.x = t[cl][e4]; o.y = t[cl][e4 + 1]; o.z = t[cl][e4 + 2]; o.w = t[cl][e4 + 3];
        *(ushort4*)(d + (size_t)(c0 + cl) * DMODEL + e0 + e4) = o;
    }
}

// ---------------- in-proj: bf16 MFMA GEMM 128x128, BK=64 (two BK=32 panels), z = dir ----------------
__global__ __launch_bounds__(256, 4) void k_mm_in(
    const u16* __restrict__ A, const u16* __restrict__ W0,
    u16* __restrict__ zb0, u16* __restrict__ xbcraw0)
{
    const int K = DMODEL;
    int dir = blockIdx.z;
    const u16* W = W0 + (size_t)dir * N_INW;
    int m0 = blockIdx.y * 128, n0 = blockIdx.x * 128;

    u16* Cout;
    int ldcc, nbase;
    if (n0 < DINNER) {
        Cout = zb0 + (size_t)dir * T * DINNER;
        ldcc = DINNER;
        nbase = n0;
    } else {
        Cout = xbcraw0 + (size_t)dir * T * CONVCH;
        ldcc = CONVCH;
        nbase = n0 - DINNER;
    }

    __shared__ u16 As[2 * 128 * 32];
    __shared__ u16 Bs[2 * 128 * 32];
    int tid = threadIdx.x;
    int lane = tid & 63;
    int wrow = ((tid >> 6) & 1) * 64, wcol = (tid >> 7) * 64;

    int srow = tid >> 2, skof = (tid & 3) * 8;
    int ar1 = m0 + srow, ar2 = ar1 + 64;
    if (dir) { ar1 = flipseq(ar1); ar2 = flipseq(ar2); }
    const u16* ga1 = A + (size_t)ar1 * K + skof;
    const u16* ga2 = A + (size_t)ar2 * K + skof;
    const u16* gb1 = W + (size_t)(n0 + srow) * K + skof;
    const u16* gb2 = gb1 + (size_t)64 * K;
    u16* la1 = As + tid * 8;
    u16* la2 = As + 2048 + tid * 8;
    u16* lb1 = Bs + tid * 8;
    u16* lb2 = Bs + 2048 + tid * 8;

    int aoff[4], boff[4];
    #pragma unroll
    for (int i = 0; i < 4; ++i) {
        aoff[i] = (wrow + i * 16 + (lane & 15)) * 32 + ((lane >> 4) * 8);
        boff[i] = (wcol + i * 16 + (lane & 15)) * 32 + ((lane >> 4) * 8);
    }

    f32x4 acc[4][4] = {};
    for (int kt = 0; kt < K; kt += 64) {
        gload16(ga1, la1);        gload16(ga2, la2);
        gload16(ga1 + 32, la1 + 4096); gload16(ga2 + 32, la2 + 4096);
        gload16(gb1, lb1);        gload16(gb2, lb2);
        gload16(gb1 + 32, lb1 + 4096); gload16(gb2 + 32, lb2 + 4096);
        ga1 += 64; ga2 += 64; gb1 += 64; gb2 += 64;
        __syncthreads();
        #pragma unroll
        for (int ks = 0; ks < 2; ++ks) {
            bf16x8 af[4], bfv[4];
            #pragma unroll
            for (int i = 0; i < 4; ++i) af[i] = *(const bf16x8*)(As + ks * 4096 + aoff[i]);
            #pragma unroll
            for (int j = 0; j < 4; ++j) bfv[j] = *(const bf16x8*)(Bs + ks * 4096 + boff[j]);
            #pragma unroll
            for (int i = 0; i < 4; ++i)
                #pragma unroll
                for (int j = 0; j < 4; ++j)
                    acc[i][j] = __builtin_amdgcn_mfma_f32_16x16x32_bf16(af[i], bfv[j], acc[i][j], 0, 0, 0);
        }
        __syncthreads();
    }

    int rbase = m0 + wrow + ((lane >> 4) << 2);
    int cbase = nbase + wcol + (lane & 15);
    #pragma unroll
    for (int i = 0; i < 4; ++i)
        #pragma unroll
        for (int j = 0; j < 4; ++j)
            #pragma unroll
            for (int r = 0; r < 4; ++r)
                Cout[(size_t)(rbase + i * 16 + r) * ldcc + cbase + j * 16] = f2b(acc[i][j][r]);
}

// ---------------- bf16 MFMA GEMM, 64x64 tile, BK=64 two-panel, z-batched, lda-aware ----------------
__global__ __launch_bounds__(256) void k_mm64(
    const u16* __restrict__ A, size_t astride, int lda,
    const u16* __restrict__ W, size_t wstride, int K,
    u16* __restrict__ Cb, int ldc, int coffStride)
{
    int dir = blockIdx.z;
    A += (size_t)dir * astride;
    W += (size_t)dir * wstride;
    int coff = dir * coffStride;

    __shared__ u16 As[2 * 64 * 32];
    __shared__ u16 Bs[2 * 64 * 32];
    int tid = threadIdx.x;
    int lane = tid & 63;
    int w = tid >> 6;
    int m0 = blockIdx.y * 64, n0 = blockIdx.x * 64;
    int wrow = (w & 1) * 32, wcol = (w >> 1) * 32;

    int srow = tid >> 2, skof = (tid & 3) * 8;
    const u16* ga = A + (size_t)(m0 + srow) * lda + skof;
    const u16* gb = W + (size_t)(n0 + srow) * K + skof;
    u16* la = As + tid * 8;
    u16* lb = Bs + tid * 8;

    int aoff[2], boff[2];
    #pragma unroll
    for (int i = 0; i < 2; ++i) {
        aoff[i] = (wrow + i * 16 + (lane & 15)) * 32 + ((lane >> 4) * 8);
        boff[i] = (wcol + i * 16 + (lane & 15)) * 32 + ((lane >> 4) * 8);
    }

    f32x4 acc[2][2] = {};
    for (int kt = 0; kt < K; kt += 64) {
        gload16(ga, la);      gload16(ga + 32, la + 2048);
        gload16(gb, lb);      gload16(gb + 32, lb + 2048);
        ga += 64; gb += 64;
        __syncthreads();
        #pragma unroll
        for (int ks = 0; ks < 2; ++ks) {
            bf16x8 af[2], bfv[2];
            #pragma unroll
            for (int i = 0; i < 2; ++i) af[i] = *(const bf16x8*)(As + ks * 2048 + aoff[i]);
            #pragma unroll
            for (int j = 0; j < 2; ++j) bfv[j] = *(const bf16x8*)(Bs + ks * 2048 + boff[j]);
            #pragma unroll
            for (int i = 0; i < 2; ++i)
                #pragma unroll
                for (int j = 0; j < 2; ++j)
                    acc[i][j] = __builtin_amdgcn_mfma_f32_16x16x32_bf16(af[i], bfv[j], acc[i][j], 0, 0, 0);
        }
        __syncthreads();
    }

    int rbase = m0 + wrow + ((lane >> 4) << 2);
    int cbase = n0 + wcol + (lane & 15);
    #pragma unroll
    for (int i = 0; i < 2; ++i)
        #pragma unroll
        for (int j = 0; j < 2; ++j)
            #pragma unroll
            for (int r = 0; r < 4; ++r)
                Cb[(size_t)(rbase + i * 16 + r) * ldc + coff + cbase + j * 16] = f2b(acc[i][j][r]);
}

// ---------------- final fused GEMM, both halves interleaved per barrier window ----------------
// out = ybb_f@Mf^T + flip(ybb_b)@Mb^T + bias + x ; 32 K-iterations instead of 64.
__global__ __launch_bounds__(256) void k_mm_fin(
    const u16* __restrict__ A1, const u16* __restrict__ A2,
    const u16* __restrict__ W,      // Mcomb: 1024 x 4096 (Mf | Mb), k-contig
    float* __restrict__ out, const float* __restrict__ bias,
    const float* __restrict__ resid)
{
    __shared__ u16 As[4 * 64 * 32];   // A1p0 | A1p1 | A2p0 | A2p1
    __shared__ u16 Bs[4 * 64 * 32];   // B1p0 | B1p1 | B2p0 | B2p1
    int tid = threadIdx.x;
    int lane = tid & 63;
    int w = tid >> 6;
    int m0 = blockIdx.y * 64, n0 = blockIdx.x * 64;
    int wrow = (w & 1) * 32, wcol = (w >> 1) * 32;

    int srow = tid >> 2, skof = (tid & 3) * 8;
    const u16* ga1 = A1 + (size_t)(m0 + srow) * DINNER + skof;
    const u16* ga2 = A2 + (size_t)flipseq(m0 + srow) * DINNER + skof;
    const u16* gb1 = W + (size_t)(n0 + srow) * 4096 + skof;
    const u16* gb2 = gb1 + 2048;
    u16* la = As + tid * 8;
    u16* lb = Bs + tid * 8;

    int aoff[2], boff[2];
    #pragma unroll
    for (int i = 0; i < 2; ++i) {
        aoff[i] = (wrow + i * 16 + (lane & 15)) * 32 + ((lane >> 4) * 8);
        boff[i] = (wcol + i * 16 + (lane & 15)) * 32 + ((lane >> 4) * 8);
    }

    f32x4 acc[2][2] = {};
    for (int kt = 0; kt < DINNER; kt += 64) {
        gload16(ga1, la);       gload16(ga1 + 32, la + 2048);
        gload16(ga2, la + 4096); gload16(ga2 + 32, la + 6144);
        gload16(gb1, lb);       gload16(gb1 + 32, lb + 2048);
        gload16(gb2, lb + 4096); gload16(gb2 + 32, lb + 6144);
        ga1 += 64; ga2 += 64; gb1 += 64; gb2 += 64;
        __syncthreads();
        #pragma unroll
        for (int half = 0; half < 2; ++half) {
            #pragma unroll
            for (int ks = 0; ks < 2; ++ks) {
                bf16x8 af[2], bfv[2];
                #pragma unroll
                for (int i = 0; i < 2; ++i)
                    af[i] = *(const bf16x8*)(As + half * 4096 + ks * 2048 + aoff[i]);
                #pragma unroll
                for (int j = 0; j < 2; ++j)
                    bfv[j] = *(const bf16x8*)(Bs + half * 4096 + ks * 2048 + boff[j]);
                #pragma unroll
                for (int i = 0; i < 2; ++i)
                    #pragma unroll
                    for (int j = 0; j < 2; ++j)
                        acc[i][j] = __builtin_amdgcn_mfma_f32_16x16x32_bf16(af[i], bfv[j], acc[i][j], 0, 0, 0);
            }
        }
        __syncthreads();
    }

    int rbase = m0 + wrow + ((lane >> 4) << 2);
    int cbase = n0 + wcol + (lane & 15);
    #pragma unroll
    for (int i = 0; i < 2; ++i)
        #pragma unroll
        for (int j = 0; j < 2; ++j)
            #pragma unroll
            for (int r = 0; r < 4; ++r) {
                int row = rbase + i * 16 + r, col = cbase + j * 16;
                out[(size_t)row * DMODEL + col] =
                    acc[i][j][r] + bias[col] + resid[(size_t)row * DMODEL + col];
            }
}

// ---------------- dt = softplus(xn . w_dt + bias), 4 rows/block, z = dir ----------------
__global__ __launch_bounds__(256) void k_dt2(
    const u16* __restrict__ xnb,
    const float* __restrict__ inw_f, const float* __restrict__ inw_b,
    const float* __restrict__ dtb_f, const float* __restrict__ dtb_b,
    float* __restrict__ dt)
{
    int dir = blockIdx.z;
    const float* wbase = dir ? inw_b : inw_f;
    const float* dtbia = dir ? dtb_b : dtb_f;
    float* dtp = dt + (size_t)dir * T * NH;

    int r0 = blockIdx.x * 4;
    __shared__ float xs[4][1024];
    int tid = threadIdx.x;
    #pragma unroll
    for (int rr = 0; rr < 4; ++rr) {
        int src = dir ? flipseq(r0 + rr) : (r0 + rr);
        ushort4 v = *(const ushort4*)(xnb + (size_t)src * DMODEL + tid * 4);
        xs[rr][tid * 4 + 0] = b2f(v.x); xs[rr][tid * 4 + 1] = b2f(v.y);
        xs[rr][tid * 4 + 2] = b2f(v.z); xs[rr][tid * 4 + 3] = b2f(v.w);
    }
    __syncthreads();
    int h = tid >> 3, part = tid & 7;
    const float* w = wbase + (size_t)(DPROJ2 + h) * DMODEL;
    float a0 = 0.f, a1 = 0.f, a2 = 0.f, a3 = 0.f;
    for (int kk = 0; kk < 128; ++kk) {
        int k = part + (kk << 3);
        float wv = w[k];
        a0 += xs[0][k] * wv; a1 += xs[1][k] * wv;
        a2 += xs[2][k] * wv; a3 += xs[3][k] * wv;
    }
    #pragma unroll
    for (int off = 4; off > 0; off >>= 1) {
        a0 += __shfl_down(a0, off, 8); a1 += __shfl_down(a1, off, 8);
        a2 += __shfl_down(a2, off, 8); a3 += __shfl_down(a3, off, 8);
    }
    if (part == 0) {
        float bsh = dtbia[h];
        float vv[4] = {a0, a1, a2, a3};
        #pragma unroll
        for (int rr = 0; rr < 4; ++rr) {
            float v = vv[rr] + bsh;
            dtp[(size_t)(r0 + rr) * NH + h] = (v > 20.f) ? v : log1pf(expf(v));
        }
    }
}

// ---------------- conv4 + silu -> bf16 xbcb; x-part * dt -> xdtb; z = dir ----------------
__global__ void k_conv(const u16* __restrict__ xraw0,
                       const float* __restrict__ cw_f, const float* __restrict__ cw_b,
                       const float* __restrict__ cb_f, const float* __restrict__ cb_b,
                       const float* __restrict__ dt0,
                       u16* __restrict__ xbcb0, u16* __restrict__ xdtb0)
{
    int dir = blockIdx.z;
    const u16* xraw = xraw0 + (size_t)dir * T * CONVCH;
    const float* cw = dir ? cw_b : cw_f;
    const float* cb = dir ? cb_b : cb_f;
    const float* dt = dt0 + (size_t)dir * T * NH;
    u16* xbcb = xbcb0 + (size_t)dir * T * CONVCH;
    u16* xdtb = xdtb0 + (size_t)dir * T * DINNER;

    int idx = blockIdx.x * blockDim.x + threadIdx.x;
    if (idx >= T * (CONVCH / 8)) return;
    int r = idx / (CONVCH / 8);
    int c8 = (idx - r * (CONVCH / 8)) * 8;
    int t = r & (SEQL - 1);
    int b0 = r - t;
    float4 cwv[8];
    #pragma unroll
    for (int j = 0; j < 8; ++j) cwv[j] = *(const float4*)(cw + (size_t)(c8 + j) * 4);
    float acc[8];
    {
        float4 c0 = *(const float4*)(cb + c8);
        float4 c1 = *(const float4*)(cb + c8 + 4);
        acc[0] = c0.x; acc[1] = c0.y; acc[2] = c0.z; acc[3] = c0.w;
        acc[4] = c1.x; acc[5] = c1.y; acc[6] = c1.z; acc[7] = c1.w;
    }
    #pragma unroll
    for (int k = 0; k < 4; ++k) {
        int tt = t + k - 3;
        if (tt < 0) continue;
        const u16* src = xraw + (size_t)(b0 + tt) * CONVCH + c8;
        ushort4 v0 = *(const ushort4*)src;
        ushort4 v1 = *(const ushort4*)(src + 4);
        float xv[8] = {b2f(v0.x), b2f(v0.y), b2f(v0.z), b2f(v0.w),
                       b2f(v1.x), b2f(v1.y), b2f(v1.z), b2f(v1.w)};
        #pragma unroll
        for (int j = 0; j < 8; ++j) {
            float wv = (k == 0) ? cwv[j].x : (k == 1) ? cwv[j].y : (k == 2) ? cwv[j].z : cwv[j].w;
            acc[j] += xv[j] * wv;
        }
    }
    ushort4 o0, o1;
    float s[8];
    #pragma unroll
    for (int j = 0; j < 8; ++j) s[j] = acc[j] / (1.f + __expf(-acc[j]));
    o0.x = f2b(s[0]); o0.y = f2b(s[1]); o0.z = f2b(s[2]); o0.w = f2b(s[3]);
    o1.x = f2b(s[4]); o1.y = f2b(s[5]); o1.z = f2b(s[6]); o1.w = f2b(s[7]);
    *(ushort4*)(xbcb + (size_t)r * CONVCH + c8) = o0;
    *(ushort4*)(xbcb + (size_t)r * CONVCH + c8 + 4) = o1;
    if (c8 < DINNER) {
        float dv = dt[(size_t)r * NH + (c8 >> 6)];
        ushort4 d0, d1;
        d0.x = f2b(s[0] * dv); d0.y = f2b(s[1] * dv); d0.z = f2b(s[2] * dv); d0.w = f2b(s[3] * dv);
        d1.x = f2b(s[4] * dv); d1.y = f2b(s[5] * dv); d1.z = f2b(s[6] * dv); d1.w = f2b(s[7] * dv);
        *(ushort4*)(xdtb + (size_t)r * DINNER + c8) = d0;
        *(ushort4*)(xdtb + (size_t)r * DINNER + c8 + 4) = d1;
    }
}

#define LDW 136
// ---------------- states + inline acs: cumsum, st = (X*dt)^T @ (B*dec); writes acs/cd; z = dir ----------------
__global__ __launch_bounds__(256) void k_states(
    const u16* __restrict__ xbcb0, const u16* __restrict__ xdtb0,
    const float* __restrict__ dt0,
    const float* __restrict__ Alog_f, const float* __restrict__ Alog_b,
    float* __restrict__ acs0, float* __restrict__ cd0, u16* __restrict__ st0)
{
    int dir = blockIdx.z;
    const u16* xbcb = xbcb0 + (size_t)dir * T * CONVCH;
    const u16* xdtb = xdtb0 + (size_t)dir * T * DINNER;
    const float* dt = dt0 + (size_t)dir * T * NH;
    const float* A_log = dir ? Alog_b : Alog_f;
    float* acs = acs0 + (size_t)dir * BATCH * NH * NCH * CHUNK;
    float* cd = cd0 + (size_t)dir * BATCH * NH * NCH;
    u16* st = st0 + (size_t)dir * N_ST;

    __shared__ u16 Bt[128 * LDW];   // Bt[n][l] = B[l][n]*dec[l]
    __shared__ u16 Xt[64 * LDW];    // Xt[p][l] = X[l][p]*dt[l]
    __shared__ float cs[128];
    __shared__ float dec_s[128];
    int tid = threadIdx.x;
    int lane = tid & 63;
    int w = tid >> 6;
    int h = blockIdx.x & 31;
    int bc = blockIdx.x >> 5;
    int c = bc & 15, b = bc >> 4;
    int row0 = b * SEQL + c * CHUNK;

    // inline acs: cumsum of A*dt over the chunk (Hillis-Steele, 128 lanes)
    if (tid < 128) {
        float Ah = -expf(A_log[h]);
        cs[tid] = Ah * dt[(size_t)(row0 + tid) * NH + h];
    }
    // stage Xt while cumsum runs its barriers
    for (int i = tid; i < 128 * 16; i += 256) {
        int l = i >> 4, pg = (i & 15) * 4;
        ushort4 v = *(const ushort4*)(xdtb + (size_t)(row0 + l) * DINNER + h * HD + pg);
        Xt[(pg + 0) * LDW + l] = v.x; Xt[(pg + 1) * LDW + l] = v.y;
        Xt[(pg + 2) * LDW + l] = v.z; Xt[(pg + 3) * LDW + l] = v.w;
    }
    __syncthreads();
    for (int off = 1; off < 128; off <<= 1) {
        float tval = 0.f;
        if (tid < 128 && tid >= off) tval = cs[tid - off];
        __syncthreads();
        if (tid < 128) cs[tid] += tval;
        __syncthreads();
    }
    size_t abase = ((size_t)(b * NH + h) * NCH + c) << 7;
    if (tid < 128) acs[abase + tid] = cs[tid];
    float a_last = cs[127];
    if (tid == 127) cd[(b * NH + h) * NCH + c] = expf(a_last);
    if (tid < 128) dec_s[tid] = __expf(a_last - cs[tid]);
    __syncthreads();
    for (int i = tid; i < 128 * 32; i += 256) {
        int l = i >> 5, ng = (i & 31) * 4;
        ushort4 v = *(const ushort4*)(xbcb + (size_t)(row0 + l) * CONVCH + DINNER + ng);
        float d = dec_s[l];
        Bt[(ng + 0) * LDW + l] = f2b(b2f(v.x) * d);
        Bt[(ng + 1) * LDW + l] = f2b(b2f(v.y) * d);
        Bt[(ng + 2) * LDW + l] = f2b(b2f(v.z) * d);
        Bt[(ng + 3) * LDW + l] = f2b(b2f(v.w) * d);
    }
    __syncthreads();
    f32x4 tacc[8] = {};
    for (int kk = 0; kk < 4; ++kk) {
        bf16x8 afs = *(const bf16x8*)(Xt + (w * 16 + (lane & 15)) * LDW
                                      + kk * 32 + (lane >> 4) * 8);
        #pragma unroll
        for (int j = 0; j < 8; ++j) {
            bf16x8 bfs = *(const bf16x8*)(Bt + (j * 16 + (lane & 15)) * LDW
                                          + kk * 32 + (lane >> 4) * 8);
            tacc[j] = __builtin_amdgcn_mfma_f32_16x16x32_bf16(afs, bfs, tacc[j], 0, 0, 0);
        }
    }
    size_t sb = (size_t)blockIdx.x * (HD * DSTATE);
    #pragma unroll
    for (int j = 0; j < 8; ++j)
        #pragma unroll
        for (int r = 0; r < 4; ++r) {
            int p = w * 16 + (lane >> 4) * 4 + r;
            int n = j * 16 + (lane & 15);
            st[sb + (size_t)p * DSTATE + n] = f2b(tacc[j][r]);
        }
}

// ---------------- inter-chunk scan (in place, bf16), both dirs ----------------
__global__ void k_scan(u16* __restrict__ st0, const float* __restrict__ cd0)
{
    int i = blockIdx.x * blockDim.x + threadIdx.x;
    if (i >= 2 * BATCH * NH * HD * DSTATE) return;
    int dir = i >> 19;                  // BATCH*NH*HD*DSTATE == 1<<19
    int j = i & ((1 << 19) - 1);
    u16* st = st0 + (size_t)dir * N_ST;
    const float* cd = cd0 + (size_t)dir * BATCH * NH * NCH;
    int n = j & 127;
    int rest = j >> 7;
    int p = rest & 63; rest >>= 6;
    int h = rest & 31;
    int b = rest >> 5;
    float s = 0.f;
    for (int c = 0; c < NCH; ++c) {
        size_t idx = ((size_t)((b * NCH + c) * NH + h) * HD + p) * DSTATE + n;
        float v = b2f(st[idx]);
        st[idx] = f2b(s);                              // prev_c
        s = s * cd[(b * NH + h) * NCH + c] + v;        // carry (fp32)
    }
}

// ---------------- fused per-(b,c,h): Y_diag + Y_off + xh*D -> y (single write); z = dir ----------------
__global__ __launch_bounds__(256) void k_chunk(
    const u16* __restrict__ xbcb0, const u16* __restrict__ xdtb0,
    const float* __restrict__ acs0, const u16* __restrict__ prev0,
    const float* __restrict__ D_f, const float* __restrict__ D_b,
    u16* __restrict__ y0)
{
    int dir = blockIdx.z;
    const u16* xbcb = xbcb0 + (size_t)dir * T * CONVCH;
    const u16* xdtb = xdtb0 + (size_t)dir * T * DINNER;
    const float* acs = acs0 + (size_t)dir * BATCH * NH * NCH * CHUNK;
    const u16* prev = prev0 + (size_t)dir * N_ST;
    const float* Dp = dir ? D_b : D_f;
    u16* y = y0 + (size_t)dir * T * DINNER;

    __shared__ u16 S0[128 * LDW];   // Bs -> Ps -> Pv(prev)
    __shared__ u16 Xt[64 * LDW];    // Xt[p][l] = X[l][p]*dt[l]
    __shared__ float acs_s[128];
    int tid = threadIdx.x;
    int lane = tid & 63;
    int w = tid >> 6;
    int h = blockIdx.x & 31;
    int bc = blockIdx.x >> 5;
    int c = bc & 15, b = bc >> 4;
    int row0 = b * SEQL + c * CHUNK;

    if (tid < 128)
        acs_s[tid] = acs[(((size_t)(b * NH + h) * NCH + c) << 7) + tid];
    for (int i = tid; i < 128 * 16; i += 256) {
        int s = i >> 4, m8 = (i & 15) * 8;
        *(uint4*)(S0 + s * LDW + m8) =
            *(const uint4*)(xbcb + (size_t)(row0 + s) * CONVCH + DINNER + m8);
    }
    for (int i = tid; i < 128 * 16; i += 256) {
        int l = i >> 4, pg = (i & 15) * 4;
        ushort4 v = *(const ushort4*)(xdtb + (size_t)(row0 + l) * DINNER + h * HD + pg);
        Xt[(pg + 0) * LDW + l] = v.x; Xt[(pg + 1) * LDW + l] = v.y;
        Xt[(pg + 2) * LDW + l] = v.z; Xt[(pg + 3) * LDW + l] = v.w;
    }
    __syncthreads();

    int wrow = (w & 1) * 64, wcol = (w >> 1) * 64;
    const u16* cbase = xbcb + (size_t)row0 * CONVCH + DINNER + DSTATE;
    f32x4 sacc[4][4] = {};
    for (int kk = 0; kk < 4; ++kk) {
        bf16x8 af[4], bfr[4];
        #pragma unroll
        for (int i = 0; i < 4; ++i)
            af[i] = *(const bf16x8*)(cbase + (size_t)(wrow + i * 16 + (lane & 15)) * CONVCH
                                     + kk * 32 + (lane >> 4) * 8);
        #pragma unroll
        for (int j = 0; j < 4; ++j)
            bfr[j] = *(const bf16x8*)(S0 + (wcol + j * 16 + (lane & 15)) * LDW
                                      + kk * 32 + (lane >> 4) * 8);
        #pragma unroll
        for (int i = 0; i < 4; ++i)
            #pragma unroll
            for (int j = 0; j < 4; ++j)
                if (wcol + j * 16 <= wrow + i * 16 + 15)
                    sacc[i][j] = __builtin_amdgcn_mfma_f32_16x16x32_bf16(af[i], bfr[j], sacc[i][j], 0, 0, 0);
    }
    __syncthreads();
    #pragma unroll
    for (int i = 0; i < 4; ++i)
        #pragma unroll
        for (int j = 0; j < 4; ++j) {
            int s = wcol + j * 16 + (lane & 15);
            #pragma unroll
            for (int r = 0; r < 4; ++r) {
                int l = wrow + i * 16 + (lane >> 4) * 4 + r;
                float v = (s <= l) ? sacc[i][j][r] * __expf(acs_s[l] - acs_s[s]) : 0.f;
                S0[l * LDW + s] = f2b(v);
            }
        }
    __syncthreads();
    f32x4 yacc[2][4] = {};
    for (int kk = 0; kk < 4; ++kk) {
        bf16x8 af[2], bfr[4];
        #pragma unroll
        for (int i = 0; i < 2; ++i)
            af[i] = *(const bf16x8*)(S0 + (w * 32 + i * 16 + (lane & 15)) * LDW
                                     + kk * 32 + (lane >> 4) * 8);
        #pragma unroll
        for (int j = 0; j < 4; ++j)
            bfr[j] = *(const bf16x8*)(Xt + (j * 16 + (lane & 15)) * LDW
                                      + kk * 32 + (lane >> 4) * 8);
        #pragma unroll
        for (int i = 0; i < 2; ++i)
            #pragma unroll
            for (int j = 0; j < 4; ++j)
                yacc[i][j] = __builtin_amdgcn_mfma_f32_16x16x32_bf16(af[i], bfr[j], yacc[i][j], 0, 0, 0);
    }
    __syncthreads();
    size_t sb = (size_t)blockIdx.x * (HD * DSTATE);
    for (int i = tid; i < 64 * 16; i += 256) {
        int p = i >> 4, m8 = (i & 15) * 8;
        *(uint4*)(S0 + p * LDW + m8) = *(const uint4*)(prev + sb + (size_t)p * DSTATE + m8);
    }
    __syncthreads();
    f32x4 oacc[2][4] = {};
    for (int kk = 0; kk < 4; ++kk) {
        bf16x8 af[2], bfr[4];
        #pragma unroll
        for (int i = 0; i < 2; ++i)
            af[i] = *(const bf16x8*)(cbase + (size_t)(w * 32 + i * 16 + (lane & 15)) * CONVCH
                                     + kk * 32 + (lane >> 4) * 8);
        #pragma unroll
        for (int j = 0; j < 4; ++j)
            bfr[j] = *(const bf16x8*)(S0 + (j * 16 + (lane & 15)) * LDW
                                      + kk * 32 + (lane >> 4) * 8);
        #pragma unroll
        for (int i = 0; i < 2; ++i)
            #pragma unroll
            for (int j = 0; j < 4; ++j)
                oacc[i][j] = __builtin_amdgcn_mfma_f32_16x16x32_bf16(af[i], bfr[j], oacc[i][j], 0, 0, 0);
    }
    float Dh = Dp[h];
    #pragma unroll
    for (int i = 0; i < 2; ++i)
        #pragma unroll
        for (int j = 0; j < 4; ++j)
            #pragma unroll
            for (int r = 0; r < 4; ++r) {
                int l = w * 32 + i * 16 + (lane >> 4) * 4 + r;
                int p = j * 16 + (lane & 15);
                float val = yacc[i][j][r] + __expf(acs_s[l]) * oacc[i][j][r]
                          + b2f(xbcb[(size_t)(row0 + l) * CONVCH + h * HD + p]) * Dh;
                y[(size_t)(row0 + l) * DINNER + h * HD + p] = f2b(val);
            }
}

// ---------------- gated rmsnorm (register-resident) -> bf16; z = dir ----------------
__global__ __launch_bounds__(256) void k_gate(
    const u16* __restrict__ y0, const u16* __restrict__ zb0,
    const float* __restrict__ gw_f, const float* __restrict__ gw_b,
    u16* __restrict__ out0)
{
    int dir = blockIdx.z;
    const u16* y = y0 + (size_t)dir * T * DINNER;
    const u16* zb = zb0 + (size_t)dir * T * DINNER;
    const float* gw = dir ? gw_b : gw_f;
    u16* out = out0 + (size_t)dir * T * DINNER;

    int r = blockIdx.x;
    int tid = threadIdx.x;
    float tv[8];
    float ss = 0.f;
    #pragma unroll
    for (int it = 0; it < 2; ++it) {
        int i = (it * 256 + tid) * 4;
        ushort4 yv = *(const ushort4*)(y + (size_t)r * DINNER + i);
        ushort4 zv = *(const ushort4*)(zb + (size_t)r * DINNER + i);
        float z0 = b2f(zv.x), z1 = b2f(zv.y), z2 = b2f(zv.z), z3 = b2f(zv.w);
        float t0 = b2f(yv.x) * (z0 / (1.f + __expf(-z0)));
        float t1 = b2f(yv.y) * (z1 / (1.f + __expf(-z1)));
        float t2 = b2f(yv.z) * (z2 / (1.f + __expf(-z2)));
        float t3 = b2f(yv.w) * (z3 / (1.f + __expf(-z3)));
        tv[it * 4 + 0] = t0; tv[it * 4 + 1] = t1; tv[it * 4 + 2] = t2; tv[it * 4 + 3] = t3;
        ss += t0 * t0 + t1 * t1 + t2 * t2 + t3 * t3;
    }
    float tot = blockReduceSum(ss);
    float sc = rsqrtf(tot / DINNER + EPS);
    #pragma unroll
    for (int it = 0; it < 2; ++it) {
        int i = (it * 256 + tid) * 4;
        ushort4 o;
        o.x = f2b(tv[it * 4 + 0] * sc * gw[i]);
        o.y = f2b(tv[it * 4 + 1] * sc * gw[i + 1]);
        o.z = f2b(tv[it * 4 + 2] * sc * gw[i + 2]);
        o.w = f2b(tv[it * 4 + 3] * sc * gw[i + 3]);
        *(ushort4*)(out + (size_t)r * DINNER + i) = o;
    }
}

// ---------------- launch ----------------
extern "C" void kernel_launch(void* const* d_in, const int* in_sizes, int n_in,
                              void* d_out, int out_size, void* d_ws, size_t ws_size,
                              hipStream_t stream)
{
    const float* x         = (const float*)d_in[0];
    const float* norm_w    = (const float*)d_in[1];
    const float* out_w_blk = (const float*)d_in[2];
    const float* out_b_blk = (const float*)d_in[3];
    const float* f_in_w    = (const float*)d_in[4];
    const float* f_conv_w  = (const float*)d_in[5];
    const float* f_conv_b  = (const float*)d_in[6];
    const float* f_dt_bias = (const float*)d_in[7];
    const float* f_A_log   = (const float*)d_in[8];
    const float* f_D       = (const float*)d_in[9];
    const float* f_gnorm_w = (const float*)d_in[10];
    const float* f_out_w   = (const float*)d_in[11];
    const float* b_in_w    = (const float*)d_in[12];
    const float* b_conv_w  = (const float*)d_in[13];
    const float* b_conv_b  = (const float*)d_in[14];
    const float* b_dt_bias = (const float*)d_in[15];
    const float* b_A_log   = (const float*)d_in[16];
    const float* b_D       = (const float*)d_in[17];
    const float* b_gnorm_w = (const float*)d_in[18];
    const float* b_out_w   = (const float*)d_in[19];
    float* out = (float*)d_out;

    // ---- workspace layout with liveness overlap (~207 MiB) ----
    char* ws = (char*)d_ws;
    u16*  xnb    = (u16*)ws;   ws += (size_t)T * DMODEL * 2;
    u16*  zb     = (u16*)ws;   ws += (size_t)2 * T * DINNER * 2;
    u16*  xbcraw = (u16*)ws;   ws += (size_t)2 * T * CONVCH * 2;   // dead after conv -> y
    u16*  xbcb   = (u16*)ws;   ws += (size_t)2 * T * CONVCH * 2;   // dead after chunk -> Mcomb
    u16*  xdtb   = (u16*)ws;   ws += (size_t)2 * T * DINNER * 2;   // dead after chunk -> ybb
    float* dtb   = (float*)ws; ws += (size_t)2 * T * NH * 4;
    float* acs   = (float*)ws; ws += (size_t)2 * BATCH * NH * NCH * CHUNK * 4;
    float* cd    = (float*)ws; ws += (size_t)2 * BATCH * NH * NCH * 4;
    u16*  stb    = (u16*)ws;   ws += (size_t)2 * N_ST * 2;
    u16*  inwb   = (u16*)ws;   ws += (size_t)2 * N_INW * 2;
    u16*  fowT2  = (u16*)ws;   ws += (size_t)2 * N_OUTW * 2;       // transposed out_w (bf16)
    u16*  owbb   = (u16*)ws;   ws += (size_t)N_OUTW * 2;           // out_w_blk bf16
    // aliases
    u16*  yb16  = xbcraw;   // Y bf16 (2*T*DINNER <= 2*T*CONVCH)
    u16*  ybb   = xdtb;     // gated-norm output
    u16*  Mcomb = xbcb;     // combined weights 1024 x 4096 (8.4 MB <= 37.7 MB)

    k_rmsnorm<<<T, 256, 0, stream>>>(x, norm_w, xnb);
    k_wprep<<<F2B_BLOCKS + TW_BLOCKS, 256, 0, stream>>>(
        f_in_w, b_in_w, out_w_blk, f_out_w, b_out_w, inwb, owbb, fowT2);

    // in-proj both dirs: z -> zb, xBC -> xbcraw
    {
        dim3 g(DPROJ2 / 128, T / 128, 2);
        k_mm_in<<<g, 256, 0, stream>>>(xnb, inwb, zb, xbcraw);
    }
    {
        dim3 g(T / 4, 1, 2);
        k_dt2<<<g, 256, 0, stream>>>(xnb, f_in_w, b_in_w, f_dt_bias, b_dt_bias, dtb);
    }
    {
        dim3 g((T * (CONVCH / 8) + 255) / 256, 1, 2);
        k_conv<<<g, 256, 0, stream>>>(xbcraw, f_conv_w, b_conv_w, f_conv_b, b_conv_b,
                                      dtb, xbcb, xdtb);
    }
    {
        dim3 g(BATCH * NCH * NH, 1, 2);
        k_states<<<g, 256, 0, stream>>>(xbcb, xdtb, dtb, f_A_log, b_A_log, acs, cd, stb);
    }
    k_scan<<<(2 * BATCH * NH * HD * DSTATE) / 256, 256, 0, stream>>>(stb, cd);
    {
        dim3 g(BATCH * NCH * NH, 1, 2);
        k_chunk<<<g, 256, 0, stream>>>(xbcb, xdtb, acs, stb, f_D, b_D, yb16);
    }
    {
        dim3 g(T, 1, 2);
        k_gate<<<g, 256, 0, stream>>>(yb16, zb, f_gnorm_w, b_gnorm_w, ybb);
    }
    // combine weights: Mf/Mb[d,c] = sum_e owb[d, dir*1024+e] * out_w[e,c]  (xbcb dead -> Mcomb)
    {
        dim3 g(DINNER / 64, DMODEL / 64, 2);
        k_mm64<<<g, 256, 0, stream>>>(owbb, (size_t)DMODEL, DINNER,
                                      fowT2, N_OUTW, DMODEL,
                                      Mcomb, 2 * DINNER, DINNER);
    }
    // final fused: out = ybb_f @ Mf^T + flip(ybb_b) @ Mb^T + bias + x (interleaved halves)
    {
        dim3 g(DMODEL / 64, T / 64, 1);
        k_mm_fin<<<g, 256, 0, stream>>>(ybb, ybb + (size_t)T * DINNER, Mcomb,
                                        out, out_b_blk, x);
    }
}

// Round 11
// 513.576 us; speedup vs baseline: 1.1511x; 1.1511x over previous
//
#include <hip/hip_runtime.h>
#include <hip/hip_bf16.h>
#include <math.h>

#define BATCH 2
#define SEQL 2048
#define T 4096            // BATCH*SEQL tokens
#define DMODEL 1024
#define DINNER 2048
#define DSTATE 128
#define NH 32
#define HD 64
#define DPROJ2 4352       // z (2048) + xBC (2304); dt handled separately in fp32
#define CONVCH 2304
#define NCH 16            // chunks per sequence
#define CHUNK 128
#define EPS 1e-5f

#define N_INW ((size_t)DPROJ2 * DMODEL)   // 4,456,448
#define N_OUTW ((size_t)DMODEL * DINNER)  // 2,097,152
#define N_ST ((size_t)BATCH * NCH * NH * HD * DSTATE)  // 8,388,608 per dir
#define F2B_BLOCKS 10752   // (2*N_INW + N_OUTW)/4/256
#define TW_BLOCKS 1024     // 32 x 16 x 2

typedef unsigned short u16;
typedef __bf16 bf16x8 __attribute__((ext_vector_type(8)));
typedef float f32x4 __attribute__((ext_vector_type(4)));

__device__ __forceinline__ u16 f2b(float f) {
    union { float f; unsigned u; } v; v.f = f;
    unsigned r = v.u + 0x7fffu + ((v.u >> 16) & 1u);
    return (u16)(r >> 16);
}
__device__ __forceinline__ float b2f(u16 b) {
    union { unsigned u; float f; } v; v.u = ((unsigned)b) << 16;
    return v.f;
}
__device__ __forceinline__ int flipseq(int r) {
    return (r & ~(SEQL - 1)) | ((SEQL - 1) - (r & (SEQL - 1)));
}
__device__ __forceinline__ void gload16(const u16* g, u16* l) {
    __builtin_amdgcn_global_load_lds(
        (const __attribute__((address_space(1))) void*)g,
        (__attribute__((address_space(3))) void*)l, 16, 0, 0);
}

// ---------------- block reduce ----------------
__device__ __forceinline__ float blockReduceSum(float v) {
    __shared__ float red_[4];
    for (int off = 32; off > 0; off >>= 1) v += __shfl_down(v, off);
    int lane = threadIdx.x & 63, wid = threadIdx.x >> 6;
    if (lane == 0) red_[wid] = v;
    __syncthreads();
    if (threadIdx.x == 0) {
        float s = 0.f;
        int nw = blockDim.x >> 6;
        for (int i = 0; i < nw; ++i) s += red_[i];
        red_[0] = s;
    }
    __syncthreads();
    return red_[0];
}

// ---------------- input rmsnorm -> bf16 ----------------
__global__ __launch_bounds__(256) void k_rmsnorm(
    const float* __restrict__ x, const float* __restrict__ w,
    u16* __restrict__ outb)
{
    int row = blockIdx.x;
    const float* xr = x + (size_t)row * DMODEL;
    float ss = 0.f;
    for (int i = threadIdx.x; i < DMODEL; i += 256) { float v = xr[i]; ss += v * v; }
    float tot = blockReduceSum(ss);
    float sc = rsqrtf(tot / DMODEL + EPS);
    for (int i = threadIdx.x; i < DMODEL; i += 256)
        outb[(size_t)row * DMODEL + i] = f2b(xr[i] * sc * w[i]);
}

// ---------------- weight prep: f2b (in_w x2, out_w_blk) + transpose out_w, one dispatch ----------------
__global__ __launch_bounds__(256) void k_wprep(
    const float* __restrict__ f_in_w, const float* __restrict__ b_in_w,
    const float* __restrict__ out_w_blk,
    const float* __restrict__ f_out_w, const float* __restrict__ b_out_w,
    u16* __restrict__ d_inwb, u16* __restrict__ d_owbb, u16* __restrict__ d_fowT)
{
    __shared__ u16 t[64][65];
    int bid = blockIdx.x;
    if (bid < F2B_BLOCKS) {
        size_t i = ((size_t)bid * 256 + threadIdx.x) * 4;
        const float* s; u16* d; size_t off;
        if (i < 2 * N_INW) {
            int dir = i >= N_INW;
            off = i - (size_t)dir * N_INW;
            s = dir ? b_in_w : f_in_w; d = d_inwb + (size_t)dir * N_INW;
        } else {
            off = i - 2 * N_INW;
            if (off >= N_OUTW) return;
            s = out_w_blk; d = d_owbb;
        }
        float4 v = *(const float4*)(s + off);
        ushort4 o;
        o.x = f2b(v.x); o.y = f2b(v.y); o.z = f2b(v.z); o.w = f2b(v.w);
        *(ushort4*)(d + off) = o;
        return;
    }
    int b2 = bid - F2B_BLOCKS;
    int dir = b2 >> 9;
    int rem = b2 & 511;
    int c0 = (rem & 31) * 64, e0 = (rem >> 5) * 64;
    const float* src = dir ? b_out_w : f_out_w;
    u16* d = d_fowT + (size_t)dir * N_OUTW;
    for (int i = threadIdx.x; i < 64 * 16; i += 256) {
        int el = i >> 4, c4 = (i & 15) * 4;
        float4 v = *(const float4*)(src + (size_t)(e0 + el) * DINNER + c0 + c4);
        t[c4 + 0][el] = f2b(v.x); t[c4 + 1][el] = f2b(v.y);
        t[c4 + 2][el] = f2b(v.z); t[c4 + 3][el] = f2b(v.w);
    }
    __syncthreads();
    for (int i = threadIdx.x; i < 64 * 16; i += 256) {
        int cl = i >> 4, e4 = (i & 15) * 4;
        ushort4 o;
        o.x = t[cl][e4]; o.y = t[cl][e4 + 1]; o.z = t[cl][e4 + 2]; o.w = t[cl][e4 + 3];
        *(ushort4*)(d + (size_t)(c0 + cl) * DMODEL + e0 + e4) = o;
    }
}

// ---------------- in-proj: bf16 MFMA GEMM 128x128, BK=64, z = dir ----------------
// Grid swizzled so CONSECUTIVE blocks share the same WEIGHT panel (n0) — weight
// tile is fetched once per co-resident group through L2 instead of ~8x from HBM.
// m0 = blockIdx.x (fast), n0 = blockIdx.y (slow).
__global__ __launch_bounds__(256, 4) void k_mm_in(
    const u16* __restrict__ A, const u16* __restrict__ W0,
    u16* __restrict__ zb0, u16* __restrict__ xbcraw0)
{
    const int K = DMODEL;
    int dir = blockIdx.z;
    const u16* W = W0 + (size_t)dir * N_INW;
    int m0 = blockIdx.x * 128, n0 = blockIdx.y * 128;

    u16* Cout;
    int ldcc, nbase;
    if (n0 < DINNER) {
        Cout = zb0 + (size_t)dir * T * DINNER;
        ldcc = DINNER;
        nbase = n0;
    } else {
        Cout = xbcraw0 + (size_t)dir * T * CONVCH;
        ldcc = CONVCH;
        nbase = n0 - DINNER;
    }

    __shared__ u16 As[2 * 128 * 32];
    __shared__ u16 Bs[2 * 128 * 32];
    int tid = threadIdx.x;
    int lane = tid & 63;
    int wrow = ((tid >> 6) & 1) * 64, wcol = (tid >> 7) * 64;

    int srow = tid >> 2, skof = (tid & 3) * 8;
    int ar1 = m0 + srow, ar2 = ar1 + 64;
    if (dir) { ar1 = flipseq(ar1); ar2 = flipseq(ar2); }
    const u16* ga1 = A + (size_t)ar1 * K + skof;
    const u16* ga2 = A + (size_t)ar2 * K + skof;
    const u16* gb1 = W + (size_t)(n0 + srow) * K + skof;
    const u16* gb2 = gb1 + (size_t)64 * K;
    u16* la1 = As + tid * 8;
    u16* la2 = As + 2048 + tid * 8;
    u16* lb1 = Bs + tid * 8;
    u16* lb2 = Bs + 2048 + tid * 8;

    int aoff[4], boff[4];
    #pragma unroll
    for (int i = 0; i < 4; ++i) {
        aoff[i] = (wrow + i * 16 + (lane & 15)) * 32 + ((lane >> 4) * 8);
        boff[i] = (wcol + i * 16 + (lane & 15)) * 32 + ((lane >> 4) * 8);
    }

    f32x4 acc[4][4] = {};
    for (int kt = 0; kt < K; kt += 64) {
        gload16(ga1, la1);        gload16(ga2, la2);
        gload16(ga1 + 32, la1 + 4096); gload16(ga2 + 32, la2 + 4096);
        gload16(gb1, lb1);        gload16(gb2, lb2);
        gload16(gb1 + 32, lb1 + 4096); gload16(gb2 + 32, lb2 + 4096);
        ga1 += 64; ga2 += 64; gb1 += 64; gb2 += 64;
        __syncthreads();
        #pragma unroll
        for (int ks = 0; ks < 2; ++ks) {
            bf16x8 af[4], bfv[4];
            #pragma unroll
            for (int i = 0; i < 4; ++i) af[i] = *(const bf16x8*)(As + ks * 4096 + aoff[i]);
            #pragma unroll
            for (int j = 0; j < 4; ++j) bfv[j] = *(const bf16x8*)(Bs + ks * 4096 + boff[j]);
            #pragma unroll
            for (int i = 0; i < 4; ++i)
                #pragma unroll
                for (int j = 0; j < 4; ++j)
                    acc[i][j] = __builtin_amdgcn_mfma_f32_16x16x32_bf16(af[i], bfv[j], acc[i][j], 0, 0, 0);
        }
        __syncthreads();
    }

    int rbase = m0 + wrow + ((lane >> 4) << 2);
    int cbase = nbase + wcol + (lane & 15);
    #pragma unroll
    for (int i = 0; i < 4; ++i)
        #pragma unroll
        for (int j = 0; j < 4; ++j)
            #pragma unroll
            for (int r = 0; r < 4; ++r)
                Cout[(size_t)(rbase + i * 16 + r) * ldcc + cbase + j * 16] = f2b(acc[i][j][r]);
}

// ---------------- bf16 MFMA GEMM, 64x64 tile, BK=64 two-panel, z-batched, lda-aware ----------------
__global__ __launch_bounds__(256) void k_mm64(
    const u16* __restrict__ A, size_t astride, int lda,
    const u16* __restrict__ W, size_t wstride, int K,
    u16* __restrict__ Cb, int ldc, int coffStride)
{
    int dir = blockIdx.z;
    A += (size_t)dir * astride;
    W += (size_t)dir * wstride;
    int coff = dir * coffStride;

    __shared__ u16 As[2 * 64 * 32];
    __shared__ u16 Bs[2 * 64 * 32];
    int tid = threadIdx.x;
    int lane = tid & 63;
    int w = tid >> 6;
    int m0 = blockIdx.y * 64, n0 = blockIdx.x * 64;
    int wrow = (w & 1) * 32, wcol = (w >> 1) * 32;

    int srow = tid >> 2, skof = (tid & 3) * 8;
    const u16* ga = A + (size_t)(m0 + srow) * lda + skof;
    const u16* gb = W + (size_t)(n0 + srow) * K + skof;
    u16* la = As + tid * 8;
    u16* lb = Bs + tid * 8;

    int aoff[2], boff[2];
    #pragma unroll
    for (int i = 0; i < 2; ++i) {
        aoff[i] = (wrow + i * 16 + (lane & 15)) * 32 + ((lane >> 4) * 8);
        boff[i] = (wcol + i * 16 + (lane & 15)) * 32 + ((lane >> 4) * 8);
    }

    f32x4 acc[2][2] = {};
    for (int kt = 0; kt < K; kt += 64) {
        gload16(ga, la);      gload16(ga + 32, la + 2048);
        gload16(gb, lb);      gload16(gb + 32, lb + 2048);
        ga += 64; gb += 64;
        __syncthreads();
        #pragma unroll
        for (int ks = 0; ks < 2; ++ks) {
            bf16x8 af[2], bfv[2];
            #pragma unroll
            for (int i = 0; i < 2; ++i) af[i] = *(const bf16x8*)(As + ks * 2048 + aoff[i]);
            #pragma unroll
            for (int j = 0; j < 2; ++j) bfv[j] = *(const bf16x8*)(Bs + ks * 2048 + boff[j]);
            #pragma unroll
            for (int i = 0; i < 2; ++i)
                #pragma unroll
                for (int j = 0; j < 2; ++j)
                    acc[i][j] = __builtin_amdgcn_mfma_f32_16x16x32_bf16(af[i], bfv[j], acc[i][j], 0, 0, 0);
        }
        __syncthreads();
    }

    int rbase = m0 + wrow + ((lane >> 4) << 2);
    int cbase = n0 + wcol + (lane & 15);
    #pragma unroll
    for (int i = 0; i < 2; ++i)
        #pragma unroll
        for (int j = 0; j < 2; ++j)
            #pragma unroll
            for (int r = 0; r < 4; ++r)
                Cb[(size_t)(rbase + i * 16 + r) * ldc + coff + cbase + j * 16] = f2b(acc[i][j][r]);
}

// ---------------- final fused GEMM, interleaved halves ----------------
__global__ __launch_bounds__(256) void k_mm_fin(
    const u16* __restrict__ A1, const u16* __restrict__ A2,
    const u16* __restrict__ W,      // Mcomb: 1024 x 4096 (Mf | Mb), k-contig
    float* __restrict__ out, const float* __restrict__ bias,
    const float* __restrict__ resid)
{
    __shared__ u16 As[4 * 64 * 32];
    __shared__ u16 Bs[4 * 64 * 32];
    int tid = threadIdx.x;
    int lane = tid & 63;
    int w = tid >> 6;
    int m0 = blockIdx.y * 64, n0 = blockIdx.x * 64;
    int wrow = (w & 1) * 32, wcol = (w >> 1) * 32;

    int srow = tid >> 2, skof = (tid & 3) * 8;
    const u16* ga1 = A1 + (size_t)(m0 + srow) * DINNER + skof;
    const u16* ga2 = A2 + (size_t)flipseq(m0 + srow) * DINNER + skof;
    const u16* gb1 = W + (size_t)(n0 + srow) * 4096 + skof;
    const u16* gb2 = gb1 + 2048;
    u16* la = As + tid * 8;
    u16* lb = Bs + tid * 8;

    int aoff[2], boff[2];
    #pragma unroll
    for (int i = 0; i < 2; ++i) {
        aoff[i] = (wrow + i * 16 + (lane & 15)) * 32 + ((lane >> 4) * 8);
        boff[i] = (wcol + i * 16 + (lane & 15)) * 32 + ((lane >> 4) * 8);
    }

    f32x4 acc[2][2] = {};
    for (int kt = 0; kt < DINNER; kt += 64) {
        gload16(ga1, la);       gload16(ga1 + 32, la + 2048);
        gload16(ga2, la + 4096); gload16(ga2 + 32, la + 6144);
        gload16(gb1, lb);       gload16(gb1 + 32, lb + 2048);
        gload16(gb2, lb + 4096); gload16(gb2 + 32, lb + 6144);
        ga1 += 64; ga2 += 64; gb1 += 64; gb2 += 64;
        __syncthreads();
        #pragma unroll
        for (int half = 0; half < 2; ++half) {
            #pragma unroll
            for (int ks = 0; ks < 2; ++ks) {
                bf16x8 af[2], bfv[2];
                #pragma unroll
                for (int i = 0; i < 2; ++i)
                    af[i] = *(const bf16x8*)(As + half * 4096 + ks * 2048 + aoff[i]);
                #pragma unroll
                for (int j = 0; j < 2; ++j)
                    bfv[j] = *(const bf16x8*)(Bs + half * 4096 + ks * 2048 + boff[j]);
                #pragma unroll
                for (int i = 0; i < 2; ++i)
                    #pragma unroll
                    for (int j = 0; j < 2; ++j)
                        acc[i][j] = __builtin_amdgcn_mfma_f32_16x16x32_bf16(af[i], bfv[j], acc[i][j], 0, 0, 0);
            }
        }
        __syncthreads();
    }

    int rbase = m0 + wrow + ((lane >> 4) << 2);
    int cbase = n0 + wcol + (lane & 15);
    #pragma unroll
    for (int i = 0; i < 2; ++i)
        #pragma unroll
        for (int j = 0; j < 2; ++j)
            #pragma unroll
            for (int r = 0; r < 4; ++r) {
                int row = rbase + i * 16 + r, col = cbase + j * 16;
                out[(size_t)row * DMODEL + col] =
                    acc[i][j][r] + bias[col] + resid[(size_t)row * DMODEL + col];
            }
}

// ---------------- dt = softplus(xn . w_dt + bias), 4 rows/block, z = dir ----------------
__global__ __launch_bounds__(256) void k_dt2(
    const u16* __restrict__ xnb,
    const float* __restrict__ inw_f, const float* __restrict__ inw_b,
    const float* __restrict__ dtb_f, const float* __restrict__ dtb_b,
    float* __restrict__ dt)
{
    int dir = blockIdx.z;
    const float* wbase = dir ? inw_b : inw_f;
    const float* dtbia = dir ? dtb_b : dtb_f;
    float* dtp = dt + (size_t)dir * T * NH;

    int r0 = blockIdx.x * 4;
    __shared__ float xs[4][1024];
    int tid = threadIdx.x;
    #pragma unroll
    for (int rr = 0; rr < 4; ++rr) {
        int src = dir ? flipseq(r0 + rr) : (r0 + rr);
        ushort4 v = *(const ushort4*)(xnb + (size_t)src * DMODEL + tid * 4);
        xs[rr][tid * 4 + 0] = b2f(v.x); xs[rr][tid * 4 + 1] = b2f(v.y);
        xs[rr][tid * 4 + 2] = b2f(v.z); xs[rr][tid * 4 + 3] = b2f(v.w);
    }
    __syncthreads();
    int h = tid >> 3, part = tid & 7;
    const float* w = wbase + (size_t)(DPROJ2 + h) * DMODEL;
    float a0 = 0.f, a1 = 0.f, a2 = 0.f, a3 = 0.f;
    for (int kk = 0; kk < 128; ++kk) {
        int k = part + (kk << 3);
        float wv = w[k];
        a0 += xs[0][k] * wv; a1 += xs[1][k] * wv;
        a2 += xs[2][k] * wv; a3 += xs[3][k] * wv;
    }
    #pragma unroll
    for (int off = 4; off > 0; off >>= 1) {
        a0 += __shfl_down(a0, off, 8); a1 += __shfl_down(a1, off, 8);
        a2 += __shfl_down(a2, off, 8); a3 += __shfl_down(a3, off, 8);
    }
    if (part == 0) {
        float bsh = dtbia[h];
        float vv[4] = {a0, a1, a2, a3};
        #pragma unroll
        for (int rr = 0; rr < 4; ++rr) {
            float v = vv[rr] + bsh;
            dtp[(size_t)(r0 + rr) * NH + h] = (v > 20.f) ? v : log1pf(expf(v));
        }
    }
}

// ---------------- conv4 + silu, 4 rows x 8 ch per thread (sliding window); z = dir ----------------
// 7 source-row reads produce 4 output rows (vs 16 reads in the 1-row version).
__global__ void k_conv(const u16* __restrict__ xraw0,
                       const float* __restrict__ cw_f, const float* __restrict__ cw_b,
                       const float* __restrict__ cb_f, const float* __restrict__ cb_b,
                       const float* __restrict__ dt0,
                       u16* __restrict__ xbcb0, u16* __restrict__ xdtb0)
{
    int dir = blockIdx.z;
    const u16* xraw = xraw0 + (size_t)dir * T * CONVCH;
    const float* cw = dir ? cw_b : cw_f;
    const float* cb = dir ? cb_b : cb_f;
    const float* dt = dt0 + (size_t)dir * T * NH;
    u16* xbcb = xbcb0 + (size_t)dir * T * CONVCH;
    u16* xdtb = xdtb0 + (size_t)dir * T * DINNER;

    int idx = blockIdx.x * blockDim.x + threadIdx.x;
    if (idx >= (T / 4) * (CONVCH / 8)) return;
    int r4 = idx / (CONVCH / 8);
    int c8 = (idx - r4 * (CONVCH / 8)) * 8;
    int r0 = r4 * 4;                  // 4 rows, all within one sequence (SEQL % 4 == 0)
    int t0 = r0 & (SEQL - 1);

    float4 cwv[8];
    #pragma unroll
    for (int j = 0; j < 8; ++j) cwv[j] = *(const float4*)(cw + (size_t)(c8 + j) * 4);
    float acc[4][8];
    {
        float4 c0 = *(const float4*)(cb + c8);
        float4 c1 = *(const float4*)(cb + c8 + 4);
        #pragma unroll
        for (int i = 0; i < 4; ++i) {
            acc[i][0] = c0.x; acc[i][1] = c0.y; acc[i][2] = c0.z; acc[i][3] = c0.w;
            acc[i][4] = c1.x; acc[i][5] = c1.y; acc[i][6] = c1.z; acc[i][7] = c1.w;
        }
    }
    // source rows s = 0..6 map to global row r0 - 3 + s; output i uses tap j = s - i
    #pragma unroll
    for (int s = 0; s < 7; ++s) {
        int tt = t0 - 3 + s;
        if (tt < 0) continue;        // pre-sequence padding (zero)
        const u16* src = xraw + (size_t)(r0 - 3 + s) * CONVCH + c8;
        ushort4 v0 = *(const ushort4*)src;
        ushort4 v1 = *(const ushort4*)(src + 4);
        float xv[8] = {b2f(v0.x), b2f(v0.y), b2f(v0.z), b2f(v0.w),
                       b2f(v1.x), b2f(v1.y), b2f(v1.z), b2f(v1.w)};
        #pragma unroll
        for (int i = 0; i < 4; ++i) {
            if (i <= s && i >= s - 3) {     // compile-time after unroll
                const int j = s - i;        // tap index 0..3
                #pragma unroll
                for (int ch = 0; ch < 8; ++ch) {
                    float wv = (j == 0) ? cwv[ch].x : (j == 1) ? cwv[ch].y
                             : (j == 2) ? cwv[ch].z : cwv[ch].w;
                    acc[i][ch] += xv[ch] * wv;
                }
            }
        }
    }
    #pragma unroll
    for (int i = 0; i < 4; ++i) {
        int r = r0 + i;
        float sgl[8];
        #pragma unroll
        for (int ch = 0; ch < 8; ++ch) sgl[ch] = acc[i][ch] / (1.f + __expf(-acc[i][ch]));
        ushort4 o0, o1;
        o0.x = f2b(sgl[0]); o0.y = f2b(sgl[1]); o0.z = f2b(sgl[2]); o0.w = f2b(sgl[3]);
        o1.x = f2b(sgl[4]); o1.y = f2b(sgl[5]); o1.z = f2b(sgl[6]); o1.w = f2b(sgl[7]);
        *(ushort4*)(xbcb + (size_t)r * CONVCH + c8) = o0;
        *(ushort4*)(xbcb + (size_t)r * CONVCH + c8 + 4) = o1;
        if (c8 < DINNER) {
            float dv = dt[(size_t)r * NH + (c8 >> 6)];
            ushort4 d0, d1;
            d0.x = f2b(sgl[0] * dv); d0.y = f2b(sgl[1] * dv);
            d0.z = f2b(sgl[2] * dv); d0.w = f2b(sgl[3] * dv);
            d1.x = f2b(sgl[4] * dv); d1.y = f2b(sgl[5] * dv);
            d1.z = f2b(sgl[6] * dv); d1.w = f2b(sgl[7] * dv);
            *(ushort4*)(xdtb + (size_t)r * DINNER + c8) = d0;
            *(ushort4*)(xdtb + (size_t)r * DINNER + c8 + 4) = d1;
        }
    }
}

#define LDW 136
// ---------------- states + inline acs: cumsum, st = (X*dt)^T @ (B*dec); z = dir ----------------
__global__ __launch_bounds__(256) void k_states(
    const u16* __restrict__ xbcb0, const u16* __restrict__ xdtb0,
    const float* __restrict__ dt0,
    const float* __restrict__ Alog_f, const float* __restrict__ Alog_b,
    float* __restrict__ acs0, float* __restrict__ cd0, u16* __restrict__ st0)
{
    int dir = blockIdx.z;
    const u16* xbcb = xbcb0 + (size_t)dir * T * CONVCH;
    const u16* xdtb = xdtb0 + (size_t)dir * T * DINNER;
    const float* dt = dt0 + (size_t)dir * T * NH;
    const float* A_log = dir ? Alog_b : Alog_f;
    float* acs = acs0 + (size_t)dir * BATCH * NH * NCH * CHUNK;
    float* cd = cd0 + (size_t)dir * BATCH * NH * NCH;
    u16* st = st0 + (size_t)dir * N_ST;

    __shared__ u16 Bt[128 * LDW];
    __shared__ u16 Xt[64 * LDW];
    __shared__ float cs[128];
    __shared__ float dec_s[128];
    int tid = threadIdx.x;
    int lane = tid & 63;
    int w = tid >> 6;
    int h = blockIdx.x & 31;
    int bc = blockIdx.x >> 5;
    int c = bc & 15, b = bc >> 4;
    int row0 = b * SEQL + c * CHUNK;

    if (tid < 128) {
        float Ah = -expf(A_log[h]);
        cs[tid] = Ah * dt[(size_t)(row0 + tid) * NH + h];
    }
    for (int i = tid; i < 128 * 16; i += 256) {
        int l = i >> 4, pg = (i & 15) * 4;
        ushort4 v = *(const ushort4*)(xdtb + (size_t)(row0 + l) * DINNER + h * HD + pg);
        Xt[(pg + 0) * LDW + l] = v.x; Xt[(pg + 1) * LDW + l] = v.y;
        Xt[(pg + 2) * LDW + l] = v.z; Xt[(pg + 3) * LDW + l] = v.w;
    }
    __syncthreads();
    for (int off = 1; off < 128; off <<= 1) {
        float tval = 0.f;
        if (tid < 128 && tid >= off) tval = cs[tid - off];
        __syncthreads();
        if (tid < 128) cs[tid] += tval;
        __syncthreads();
    }
    size_t abase = ((size_t)(b * NH + h) * NCH + c) << 7;
    if (tid < 128) acs[abase + tid] = cs[tid];
    float a_last = cs[127];
    if (tid == 127) cd[(b * NH + h) * NCH + c] = expf(a_last);
    if (tid < 128) dec_s[tid] = __expf(a_last - cs[tid]);
    __syncthreads();
    for (int i = tid; i < 128 * 32; i += 256) {
        int l = i >> 5, ng = (i & 31) * 4;
        ushort4 v = *(const ushort4*)(xbcb + (size_t)(row0 + l) * CONVCH + DINNER + ng);
        float d = dec_s[l];
        Bt[(ng + 0) * LDW + l] = f2b(b2f(v.x) * d);
        Bt[(ng + 1) * LDW + l] = f2b(b2f(v.y) * d);
        Bt[(ng + 2) * LDW + l] = f2b(b2f(v.z) * d);
        Bt[(ng + 3) * LDW + l] = f2b(b2f(v.w) * d);
    }
    __syncthreads();
    f32x4 tacc[8] = {};
    for (int kk = 0; kk < 4; ++kk) {
        bf16x8 afs = *(const bf16x8*)(Xt + (w * 16 + (lane & 15)) * LDW
                                      + kk * 32 + (lane >> 4) * 8);
        #pragma unroll
        for (int j = 0; j < 8; ++j) {
            bf16x8 bfs = *(const bf16x8*)(Bt + (j * 16 + (lane & 15)) * LDW
                                          + kk * 32 + (lane >> 4) * 8);
            tacc[j] = __builtin_amdgcn_mfma_f32_16x16x32_bf16(afs, bfs, tacc[j], 0, 0, 0);
        }
    }
    size_t sb = (size_t)blockIdx.x * (HD * DSTATE);
    #pragma unroll
    for (int j = 0; j < 8; ++j)
        #pragma unroll
        for (int r = 0; r < 4; ++r) {
            int p = w * 16 + (lane >> 4) * 4 + r;
            int n = j * 16 + (lane & 15);
            st[sb + (size_t)p * DSTATE + n] = f2b(tacc[j][r]);
        }
}

// ---------------- inter-chunk scan (in place, bf16), both dirs ----------------
__global__ void k_scan(u16* __restrict__ st0, const float* __restrict__ cd0)
{
    int i = blockIdx.x * blockDim.x + threadIdx.x;
    if (i >= 2 * BATCH * NH * HD * DSTATE) return;
    int dir = i >> 19;
    int j = i & ((1 << 19) - 1);
    u16* st = st0 + (size_t)dir * N_ST;
    const float* cd = cd0 + (size_t)dir * BATCH * NH * NCH;
    int n = j & 127;
    int rest = j >> 7;
    int p = rest & 63; rest >>= 6;
    int h = rest & 31;
    int b = rest >> 5;
    float s = 0.f;
    for (int c = 0; c < NCH; ++c) {
        size_t idx = ((size_t)((b * NCH + c) * NH + h) * HD + p) * DSTATE + n;
        float v = b2f(st[idx]);
        st[idx] = f2b(s);
        s = s * cd[(b * NH + h) * NCH + c] + v;
    }
}

// ---------------- fused per-(b,c,h): Y_diag + Y_off + xh*D -> y (single write); z = dir ----------------
__global__ __launch_bounds__(256) void k_chunk(
    const u16* __restrict__ xbcb0, const u16* __restrict__ xdtb0,
    const float* __restrict__ acs0, const u16* __restrict__ prev0,
    const float* __restrict__ D_f, const float* __restrict__ D_b,
    u16* __restrict__ y0)
{
    int dir = blockIdx.z;
    const u16* xbcb = xbcb0 + (size_t)dir * T * CONVCH;
    const u16* xdtb = xdtb0 + (size_t)dir * T * DINNER;
    const float* acs = acs0 + (size_t)dir * BATCH * NH * NCH * CHUNK;
    const u16* prev = prev0 + (size_t)dir * N_ST;
    const float* Dp = dir ? D_b : D_f;
    u16* y = y0 + (size_t)dir * T * DINNER;

    __shared__ u16 S0[128 * LDW];
    __shared__ u16 Xt[64 * LDW];
    __shared__ float acs_s[128];
    int tid = threadIdx.x;
    int lane = tid & 63;
    int w = tid >> 6;
    int h = blockIdx.x & 31;
    int bc = blockIdx.x >> 5;
    int c = bc & 15, b = bc >> 4;
    int row0 = b * SEQL + c * CHUNK;

    if (tid < 128)
        acs_s[tid] = acs[(((size_t)(b * NH + h) * NCH + c) << 7) + tid];
    for (int i = tid; i < 128 * 16; i += 256) {
        int s = i >> 4, m8 = (i & 15) * 8;
        *(uint4*)(S0 + s * LDW + m8) =
            *(const uint4*)(xbcb + (size_t)(row0 + s) * CONVCH + DINNER + m8);
    }
    for (int i = tid; i < 128 * 16; i += 256) {
        int l = i >> 4, pg = (i & 15) * 4;
        ushort4 v = *(const ushort4*)(xdtb + (size_t)(row0 + l) * DINNER + h * HD + pg);
        Xt[(pg + 0) * LDW + l] = v.x; Xt[(pg + 1) * LDW + l] = v.y;
        Xt[(pg + 2) * LDW + l] = v.z; Xt[(pg + 3) * LDW + l] = v.w;
    }
    __syncthreads();

    int wrow = (w & 1) * 64, wcol = (w >> 1) * 64;
    const u16* cbase = xbcb + (size_t)row0 * CONVCH + DINNER + DSTATE;
    f32x4 sacc[4][4] = {};
    for (int kk = 0; kk < 4; ++kk) {
        bf16x8 af[4], bfr[4];
        #pragma unroll
        for (int i = 0; i < 4; ++i)
            af[i] = *(const bf16x8*)(cbase + (size_t)(wrow + i * 16 + (lane & 15)) * CONVCH
                                     + kk * 32 + (lane >> 4) * 8);
        #pragma unroll
        for (int j = 0; j < 4; ++j)
            bfr[j] = *(const bf16x8*)(S0 + (wcol + j * 16 + (lane & 15)) * LDW
                                      + kk * 32 + (lane >> 4) * 8);
        #pragma unroll
        for (int i = 0; i < 4; ++i)
            #pragma unroll
            for (int j = 0; j < 4; ++j)
                if (wcol + j * 16 <= wrow + i * 16 + 15)
                    sacc[i][j] = __builtin_amdgcn_mfma_f32_16x16x32_bf16(af[i], bfr[j], sacc[i][j], 0, 0, 0);
    }
    __syncthreads();
    #pragma unroll
    for (int i = 0; i < 4; ++i)
        #pragma unroll
        for (int j = 0; j < 4; ++j) {
            int s = wcol + j * 16 + (lane & 15);
            #pragma unroll
            for (int r = 0; r < 4; ++r) {
                int l = wrow + i * 16 + (lane >> 4) * 4 + r;
                float v = (s <= l) ? sacc[i][j][r] * __expf(acs_s[l] - acs_s[s]) : 0.f;
                S0[l * LDW + s] = f2b(v);
            }
        }
    __syncthreads();
    f32x4 yacc[2][4] = {};
    for (int kk = 0; kk < 4; ++kk) {
        bf16x8 af[2], bfr[4];
        #pragma unroll
        for (int i = 0; i < 2; ++i)
            af[i] = *(const bf16x8*)(S0 + (w * 32 + i * 16 + (lane & 15)) * LDW
                                     + kk * 32 + (lane >> 4) * 8);
        #pragma unroll
        for (int j = 0; j < 4; ++j)
            bfr[j] = *(const bf16x8*)(Xt + (j * 16 + (lane & 15)) * LDW
                                      + kk * 32 + (lane >> 4) * 8);
        #pragma unroll
        for (int i = 0; i < 2; ++i)
            #pragma unroll
            for (int j = 0; j < 4; ++j)
                yacc[i][j] = __builtin_amdgcn_mfma_f32_16x16x32_bf16(af[i], bfr[j], yacc[i][j], 0, 0, 0);
    }
    __syncthreads();
    size_t sb = (size_t)blockIdx.x * (HD * DSTATE);
    for (int i = tid; i < 64 * 16; i += 256) {
        int p = i >> 4, m8 = (i & 15) * 8;
        *(uint4*)(S0 + p * LDW + m8) = *(const uint4*)(prev + sb + (size_t)p * DSTATE + m8);
    }
    __syncthreads();
    f32x4 oacc[2][4] = {};
    for (int kk = 0; kk < 4; ++kk) {
        bf16x8 af[2], bfr[4];
        #pragma unroll
        for (int i = 0; i < 2; ++i)
            af[i] = *(const bf16x8*)(cbase + (size_t)(w * 32 + i * 16 + (lane & 15)) * CONVCH
                                     + kk * 32 + (lane >> 4) * 8);
        #pragma unroll
        for (int j = 0; j < 4; ++j)
            bfr[j] = *(const bf16x8*)(S0 + (j * 16 + (lane & 15)) * LDW
                                      + kk * 32 + (lane >> 4) * 8);
        #pragma unroll
        for (int i = 0; i < 2; ++i)
            #pragma unroll
            for (int j = 0; j < 4; ++j)
                oacc[i][j] = __builtin_amdgcn_mfma_f32_16x16x32_bf16(af[i], bfr[j], oacc[i][j], 0, 0, 0);
    }
    float Dh = Dp[h];
    #pragma unroll
    for (int i = 0; i < 2; ++i)
        #pragma unroll
        for (int j = 0; j < 4; ++j)
            #pragma unroll
            for (int r = 0; r < 4; ++r) {
                int l = w * 32 + i * 16 + (lane >> 4) * 4 + r;
                int p = j * 16 + (lane & 15);
                float val = yacc[i][j][r] + __expf(acs_s[l]) * oacc[i][j][r]
                          + b2f(xbcb[(size_t)(row0 + l) * CONVCH + h * HD + p]) * Dh;
                y[(size_t)(row0 + l) * DINNER + h * HD + p] = f2b(val);
            }
}

// ---------------- gated rmsnorm (register-resident) -> bf16; z = dir ----------------
__global__ __launch_bounds__(256) void k_gate(
    const u16* __restrict__ y0, const u16* __restrict__ zb0,
    const float* __restrict__ gw_f, const float* __restrict__ gw_b,
    u16* __restrict__ out0)
{
    int dir = blockIdx.z;
    const u16* y = y0 + (size_t)dir * T * DINNER;
    const u16* zb = zb0 + (size_t)dir * T * DINNER;
    const float* gw = dir ? gw_b : gw_f;
    u16* out = out0 + (size_t)dir * T * DINNER;

    int r = blockIdx.x;
    int tid = threadIdx.x;
    float tv[8];
    float ss = 0.f;
    #pragma unroll
    for (int it = 0; it < 2; ++it) {
        int i = (it * 256 + tid) * 4;
        ushort4 yv = *(const ushort4*)(y + (size_t)r * DINNER + i);
        ushort4 zv = *(const ushort4*)(zb + (size_t)r * DINNER + i);
        float z0 = b2f(zv.x), z1 = b2f(zv.y), z2 = b2f(zv.z), z3 = b2f(zv.w);
        float t0 = b2f(yv.x) * (z0 / (1.f + __expf(-z0)));
        float t1 = b2f(yv.y) * (z1 / (1.f + __expf(-z1)));
        float t2 = b2f(yv.z) * (z2 / (1.f + __expf(-z2)));
        float t3 = b2f(yv.w) * (z3 / (1.f + __expf(-z3)));
        tv[it * 4 + 0] = t0; tv[it * 4 + 1] = t1; tv[it * 4 + 2] = t2; tv[it * 4 + 3] = t3;
        ss += t0 * t0 + t1 * t1 + t2 * t2 + t3 * t3;
    }
    float tot = blockReduceSum(ss);
    float sc = rsqrtf(tot / DINNER + EPS);
    #pragma unroll
    for (int it = 0; it < 2; ++it) {
        int i = (it * 256 + tid) * 4;
        ushort4 o;
        o.x = f2b(tv[it * 4 + 0] * sc * gw[i]);
        o.y = f2b(tv[it * 4 + 1] * sc * gw[i + 1]);
        o.z = f2b(tv[it * 4 + 2] * sc * gw[i + 2]);
        o.w = f2b(tv[it * 4 + 3] * sc * gw[i + 3]);
        *(ushort4*)(out + (size_t)r * DINNER + i) = o;
    }
}

// ---------------- launch ----------------
extern "C" void kernel_launch(void* const* d_in, const int* in_sizes, int n_in,
                              void* d_out, int out_size, void* d_ws, size_t ws_size,
                              hipStream_t stream)
{
    const float* x         = (const float*)d_in[0];
    const float* norm_w    = (const float*)d_in[1];
    const float* out_w_blk = (const float*)d_in[2];
    const float* out_b_blk = (const float*)d_in[3];
    const float* f_in_w    = (const float*)d_in[4];
    const float* f_conv_w  = (const float*)d_in[5];
    const float* f_conv_b  = (const float*)d_in[6];
    const float* f_dt_bias = (const float*)d_in[7];
    const float* f_A_log   = (const float*)d_in[8];
    const float* f_D       = (const float*)d_in[9];
    const float* f_gnorm_w = (const float*)d_in[10];
    const float* f_out_w   = (const float*)d_in[11];
    const float* b_in_w    = (const float*)d_in[12];
    const float* b_conv_w  = (const float*)d_in[13];
    const float* b_conv_b  = (const float*)d_in[14];
    const float* b_dt_bias = (const float*)d_in[15];
    const float* b_A_log   = (const float*)d_in[16];
    const float* b_D       = (const float*)d_in[17];
    const float* b_gnorm_w = (const float*)d_in[18];
    const float* b_out_w   = (const float*)d_in[19];
    float* out = (float*)d_out;

    // ---- workspace layout with liveness overlap (~207 MiB) ----
    char* ws = (char*)d_ws;
    u16*  xnb    = (u16*)ws;   ws += (size_t)T * DMODEL * 2;
    u16*  zb     = (u16*)ws;   ws += (size_t)2 * T * DINNER * 2;
    u16*  xbcraw = (u16*)ws;   ws += (size_t)2 * T * CONVCH * 2;   // dead after conv -> y
    u16*  xbcb   = (u16*)ws;   ws += (size_t)2 * T * CONVCH * 2;   // dead after chunk -> Mcomb
    u16*  xdtb   = (u16*)ws;   ws += (size_t)2 * T * DINNER * 2;   // dead after chunk -> ybb
    float* dtb   = (float*)ws; ws += (size_t)2 * T * NH * 4;
    float* acs   = (float*)ws; ws += (size_t)2 * BATCH * NH * NCH * CHUNK * 4;
    float* cd    = (float*)ws; ws += (size_t)2 * BATCH * NH * NCH * 4;
    u16*  stb    = (u16*)ws;   ws += (size_t)2 * N_ST * 2;
    u16*  inwb   = (u16*)ws;   ws += (size_t)2 * N_INW * 2;
    u16*  fowT2  = (u16*)ws;   ws += (size_t)2 * N_OUTW * 2;
    u16*  owbb   = (u16*)ws;   ws += (size_t)N_OUTW * 2;
    // aliases
    u16*  yb16  = xbcraw;
    u16*  ybb   = xdtb;
    u16*  Mcomb = xbcb;

    k_rmsnorm<<<T, 256, 0, stream>>>(x, norm_w, xnb);
    k_wprep<<<F2B_BLOCKS + TW_BLOCKS, 256, 0, stream>>>(
        f_in_w, b_in_w, out_w_blk, f_out_w, b_out_w, inwb, owbb, fowT2);

    // in-proj both dirs (swizzled grid: x = m-panel fast, y = n/weight-panel slow)
    {
        dim3 g(T / 128, DPROJ2 / 128, 2);
        k_mm_in<<<g, 256, 0, stream>>>(xnb, inwb, zb, xbcraw);
    }
    {
        dim3 g(T / 4, 1, 2);
        k_dt2<<<g, 256, 0, stream>>>(xnb, f_in_w, b_in_w, f_dt_bias, b_dt_bias, dtb);
    }
    {
        dim3 g(((T / 4) * (CONVCH / 8) + 255) / 256, 1, 2);
        k_conv<<<g, 256, 0, stream>>>(xbcraw, f_conv_w, b_conv_w, f_conv_b, b_conv_b,
                                      dtb, xbcb, xdtb);
    }
    {
        dim3 g(BATCH * NCH * NH, 1, 2);
        k_states<<<g, 256, 0, stream>>>(xbcb, xdtb, dtb, f_A_log, b_A_log, acs, cd, stb);
    }
    k_scan<<<(2 * BATCH * NH * HD * DSTATE) / 256, 256, 0, stream>>>(stb, cd);
    {
        dim3 g(BATCH * NCH * NH, 1, 2);
        k_chunk<<<g, 256, 0, stream>>>(xbcb, xdtb, acs, stb, f_D, b_D, yb16);
    }
    {
        dim3 g(T, 1, 2);
        k_gate<<<g, 256, 0, stream>>>(yb16, zb, f_gnorm_w, b_gnorm_w, ybb);
    }
    {
        dim3 g(DINNER / 64, DMODEL / 64, 2);
        k_mm64<<<g, 256, 0, stream>>>(owbb, (size_t)DMODEL, DINNER,
                                      fowT2, N_OUTW, DMODEL,
                                      Mcomb, 2 * DINNER, DINNER);
    }
    {
        dim3 g(DMODEL / 64, T / 64, 1);
        k_mm_fin<<<g, 256, 0, stream>>>(ybb, ybb + (size_t)T * DINNER, Mcomb,
                                        out, out_b_blk, x);
    }
}